// Round 2
// baseline (186.274 us; speedup 1.0000x reference)
//
#include <hip/hip_runtime.h>
#include <math.h>

#define B_ 64
#define S_ 512
#define N_ 24
#define H_ 768
#define C_ 6
#define CHUNKS 16                       // blocks per batch
#define TOK_PER_BLOCK (S_ / CHUNKS)     // 32 tokens per block
#define TOK_PER_WAVE (TOK_PER_BLOCK/4)  // 8 tokens per wave

// Per-token: per-lane partial dot (x chunk . W chunk) for 6 channels,
// accumulated into LDS acc[seg][c][lane] with fire-and-forget ds_add_f32.
// No cross-lane reduction, no global atomics on the token critical path.
__device__ __forceinline__ void do_token(const float4 x[3], const float4 w[3][C_],
                                         int seg, int lane, float* acc) {
  float a[C_];
#pragma unroll
  for (int c = 0; c < C_; ++c) a[c] = 0.f;
#pragma unroll
  for (int k = 0; k < 3; ++k)
#pragma unroll
    for (int c = 0; c < C_; ++c)
      a[c] += x[k].x * w[k][c].x + x[k].y * w[k][c].y +
              x[k].z * w[k][c].z + x[k].w * w[k][c].w;
#pragma unroll
  for (int c = 0; c < C_; ++c)
    atomicAdd(&acc[(seg * C_ + c) * 64 + lane], a[c]);  // LDS atomic, bank=lane%32 (2-way free)
}

__global__ __launch_bounds__(256, 4) void seg_proj_kernel(
    const float* __restrict__ lhs, const int* __restrict__ st,
    const float* __restrict__ W, float* __restrict__ outbuf, int use_atomic) {
  __shared__ float acc[N_ * C_ * 64];  // 36 KB -> 4 blocks/CU
  const int tid = threadIdx.x;
  const int lane = tid & 63;
  const int wave = tid >> 6;
  const int b = blockIdx.x / CHUNKS;
  const int chunk = blockIdx.x % CHUNKS;

  for (int i = tid; i < N_ * C_ * 64; i += 256) acc[i] = 0.f;

  // boundaries resident in lanes: segment id via ballot+popcount (no loads per token)
  int stb_l = st[b * N_ + (lane < N_ ? lane : N_ - 1)];
  int last = __shfl(stb_l, N_ - 1, 64);

  const float4* W4 = (const float4*)W;
  float4 w[3][C_];
#pragma unroll
  for (int k = 0; k < 3; ++k)
#pragma unroll
    for (int c = 0; c < C_; ++c)
      w[k][c] = W4[c * (H_ / 4) + k * 64 + lane];

  __syncthreads();

  const int s_base = chunk * TOK_PER_BLOCK + wave * TOK_PER_WAVE;
#pragma unroll
  for (int g = 0; g < TOK_PER_WAVE / 2; ++g) {
    const int s0 = s_base + g * 2;
    const bool a0 = (s0 <= last);          // wave-uniform
    const bool a1 = (s0 + 1 <= last);
    const float4* x4 = (const float4*)(lhs + ((size_t)b * S_ + s0) * H_);
    float4 x0[3], x1[3];
    if (a0) {
      x0[0] = x4[lane]; x0[1] = x4[64 + lane]; x0[2] = x4[128 + lane];
    }
    if (a1) {
      x1[0] = x4[192 + lane]; x1[1] = x4[256 + lane]; x1[2] = x4[320 + lane];
    }
    if (a0) {
      unsigned long long m = __ballot(lane < N_ && stb_l < s0);
      do_token(x0, w, (int)__popcll(m), lane, acc);
    }
    if (a1) {
      unsigned long long m = __ballot(lane < N_ && stb_l < s0 + 1);
      do_token(x1, w, (int)__popcll(m), lane, acc);
    }
  }

  __syncthreads();
  // block reduce: 144 threads each sum 64 lane-partials (skewed start: no bank conflicts)
  if (tid < N_ * C_) {
    float v = 0.f;
    const int base = tid * 64;
#pragma unroll 8
    for (int i = 0; i < 64; ++i) v += acc[base + ((i + tid) & 63)];
    if (use_atomic)
      atomicAdd(&outbuf[b * N_ * C_ + tid], v);
    else
      outbuf[(size_t)blockIdx.x * (N_ * C_) + tid] = v;
  }
}

__global__ __launch_bounds__(256) void finalize_kernel(
    const float* __restrict__ buf, const int* __restrict__ st,
    const float* __restrict__ bias, float* __restrict__ out, int use_atomic) {
  int idx = blockIdx.x * blockDim.x + threadIdx.x;
  if (idx >= B_ * N_ * C_) return;
  int c = idx % C_;
  int j = (idx / C_) % N_;
  int b = idx / (N_ * C_);
  float ssum;
  if (use_atomic) {
    ssum = buf[idx];
  } else {
    ssum = 0.f;
#pragma unroll
    for (int k = 0; k < CHUNKS; ++k)
      ssum += buf[(size_t)(b * CHUNKS + k) * (N_ * C_) + j * C_ + c];
  }
  int end = st[b * N_ + j];
  int prev = (j == 0) ? -1 : st[b * N_ + j - 1];
  float len = (float)(end - prev);
  float logit = ssum / len + bias[c];
  float p = 1.0f / (1.0f + expf(-logit));
  if (end > 500) {
    float cl = (c < 3) ? 0.1f : (c == 3 ? 0.3f : (c == 4 ? 0.8f : 0.01f));
    float cm = (c < 3) ? 0.1f : (c == 3 ? 0.8f : (c == 4 ? 0.3f : 0.01f));
    p = (j == N_ - 1) ? cl : cm;
  }
  out[idx] = p;
}

extern "C" void kernel_launch(void* const* d_in, const int* in_sizes, int n_in,
                              void* d_out, int out_size, void* d_ws, size_t ws_size,
                              hipStream_t stream) {
  const float* lhs  = (const float*)d_in[0];  // [B,S,H] fp32
  const int*   st   = (const int*)d_in[1];    // [B,N] int32
  const float* W    = (const float*)d_in[2];  // [C,H] fp32
  const float* bias = (const float*)d_in[3];  // [C] fp32

  const size_t need = (size_t)B_ * CHUNKS * N_ * C_ * sizeof(float);  // 576 KB
  const int use_atomic = (ws_size < need) ? 1 : 0;
  if (use_atomic)
    hipMemsetAsync(d_ws, 0, (size_t)B_ * N_ * C_ * sizeof(float), stream);

  seg_proj_kernel<<<B_ * CHUNKS, 256, 0, stream>>>(lhs, st, W, (float*)d_ws, use_atomic);
  finalize_kernel<<<(B_ * N_ * C_ + 255) / 256, 256, 0, stream>>>(
      (float*)d_ws, st, bias, (float*)d_out, use_atomic);
}

// Round 3
// 153.898 us; speedup vs baseline: 1.2104x; 1.2104x over previous
//
#include <hip/hip_runtime.h>
#include <math.h>

#define B_ 64
#define S_ 512
#define N_ 24
#define H_ 768
#define C_ 6
#define CHUNKS 16                        // blocks per batch
#define TOK_PER_BLOCK (S_ / CHUNKS)      // 32 tokens per block
#define TOK_PER_WAVE (TOK_PER_BLOCK / 4) // 8 contiguous tokens per wave

// One wave handles 8 contiguous tokens. Lane holds an H-chunk of W in regs
// (pinned via asm so the compiler cannot rematerialize the loads), prefetches
// all 24 float4s of token data upfront (24 loads in flight), accumulates a
// per-lane per-segment partial in registers, and flushes to LDS only when the
// (wave-uniform) segment id changes.
__global__ __launch_bounds__(256, 2) void seg_proj_kernel(
    const float* __restrict__ lhs, const int* __restrict__ st,
    const float* __restrict__ W, float* __restrict__ outbuf, int use_atomic) {
  __shared__ float acc[N_ * C_ * 64];  // 36 KB
  const int tid = threadIdx.x;
  const int lane = tid & 63;
  const int wave = tid >> 6;
  const int b = blockIdx.x / CHUNKS;
  const int chunk = blockIdx.x % CHUNKS;

  // zero LDS accumulators (2304 float4s / 256 threads = 9 each)
  float4* accv = (float4*)acc;
#pragma unroll
  for (int i = 0; i < 9; ++i)
    accv[i * 256 + tid] = make_float4(0.f, 0.f, 0.f, 0.f);

  // boundaries resident in lanes (sentinel for lanes >= 24)
  int stb_l = (lane < N_) ? st[b * N_ + lane] : 0x7fffffff;

  // W fragment: lane holds W[c][k*256 + lane*4 .. +3], k=0..2, c=0..5 (72 VGPRs)
  const float4* W4 = (const float4*)W;
  float4 w[3][C_];
#pragma unroll
  for (int k = 0; k < 3; ++k)
#pragma unroll
    for (int c = 0; c < C_; ++c)
      w[k][c] = W4[c * (H_ / 4) + k * 64 + lane];
  // pin: forbid rematerialization of the W loads (24 operands per asm stmt)
#pragma unroll
  for (int k = 0; k < 3; ++k)
    asm volatile("" : "+v"(w[k][0].x), "+v"(w[k][0].y), "+v"(w[k][0].z), "+v"(w[k][0].w),
                       "+v"(w[k][1].x), "+v"(w[k][1].y), "+v"(w[k][1].z), "+v"(w[k][1].w),
                       "+v"(w[k][2].x), "+v"(w[k][2].y), "+v"(w[k][2].z), "+v"(w[k][2].w),
                       "+v"(w[k][3].x), "+v"(w[k][3].y), "+v"(w[k][3].z), "+v"(w[k][3].w),
                       "+v"(w[k][4].x), "+v"(w[k][4].y), "+v"(w[k][4].z), "+v"(w[k][4].w),
                       "+v"(w[k][5].x), "+v"(w[k][5].y), "+v"(w[k][5].z), "+v"(w[k][5].w));

  __syncthreads();

  // prefetch all 8 tokens (24 independent 1-KiB wave loads in flight)
  const int s_base = chunk * TOK_PER_BLOCK + wave * TOK_PER_WAVE;
  const float4* x4 = (const float4*)(lhs + ((size_t)b * S_ + s_base) * H_);
  float4 x[TOK_PER_WAVE][3];
#pragma unroll
  for (int t = 0; t < TOK_PER_WAVE; ++t) {
    x[t][0] = x4[t * 192 + lane];
    x[t][1] = x4[t * 192 + 64 + lane];
    x[t][2] = x4[t * 192 + 128 + lane];
  }

  float racc[C_] = {0.f, 0.f, 0.f, 0.f, 0.f, 0.f};
  int cur_seg = N_;  // sentinel: nothing pending
#pragma unroll
  for (int t = 0; t < TOK_PER_WAVE; ++t) {
    const int s = s_base + t;
    // segment id = count of boundaries < s (wave-uniform)
    const int seg = (int)__popcll(__ballot(stb_l < s));
    if (seg != cur_seg) {  // rare: ~1.4 times per wave
      if (cur_seg < N_) {
#pragma unroll
        for (int c = 0; c < C_; ++c)
          atomicAdd(&acc[(cur_seg * C_ + c) * 64 + lane], racc[c]);
      }
#pragma unroll
      for (int c = 0; c < C_; ++c) racc[c] = 0.f;
      cur_seg = seg;
    }
    // tokens past the last boundary have seg==24; they accumulate into racc
    // but cur_seg==24 is never flushed, so they are ignored (~4% wasted FMAs).
#pragma unroll
    for (int k = 0; k < 3; ++k)
#pragma unroll
      for (int c = 0; c < C_; ++c)
        racc[c] += x[t][k].x * w[k][c].x + x[t][k].y * w[k][c].y +
                   x[t][k].z * w[k][c].z + x[t][k].w * w[k][c].w;
  }
  if (cur_seg < N_) {
#pragma unroll
    for (int c = 0; c < C_; ++c)
      atomicAdd(&acc[(cur_seg * C_ + c) * 64 + lane], racc[c]);
  }

  __syncthreads();
  // block reduce: 144 threads each sum 64 lane-partials (skewed: conflict-free)
  if (tid < N_ * C_) {
    float v = 0.f;
    const int base = tid * 64;
#pragma unroll 8
    for (int i = 0; i < 64; ++i) v += acc[base + ((i + tid) & 63)];
    if (use_atomic)
      atomicAdd(&outbuf[b * N_ * C_ + tid], v);
    else
      outbuf[(size_t)blockIdx.x * (N_ * C_) + tid] = v;
  }
}

__global__ __launch_bounds__(256) void finalize_kernel(
    const float* __restrict__ buf, const int* __restrict__ st,
    const float* __restrict__ bias, float* __restrict__ out, int use_atomic) {
  int idx = blockIdx.x * blockDim.x + threadIdx.x;
  if (idx >= B_ * N_ * C_) return;
  int c = idx % C_;
  int j = (idx / C_) % N_;
  int b = idx / (N_ * C_);
  float ssum;
  if (use_atomic) {
    ssum = buf[idx];
  } else {
    ssum = 0.f;
#pragma unroll
    for (int k = 0; k < CHUNKS; ++k)
      ssum += buf[(size_t)(b * CHUNKS + k) * (N_ * C_) + j * C_ + c];
  }
  int end = st[b * N_ + j];
  int prev = (j == 0) ? -1 : st[b * N_ + j - 1];
  float len = (float)(end - prev);
  float logit = ssum / len + bias[c];
  float p = 1.0f / (1.0f + expf(-logit));
  if (end > 500) {
    float cl = (c < 3) ? 0.1f : (c == 3 ? 0.3f : (c == 4 ? 0.8f : 0.01f));
    float cm = (c < 3) ? 0.1f : (c == 3 ? 0.8f : (c == 4 ? 0.3f : 0.01f));
    p = (j == N_ - 1) ? cl : cm;
  }
  out[idx] = p;
}

extern "C" void kernel_launch(void* const* d_in, const int* in_sizes, int n_in,
                              void* d_out, int out_size, void* d_ws, size_t ws_size,
                              hipStream_t stream) {
  const float* lhs  = (const float*)d_in[0];  // [B,S,H] fp32
  const int*   st   = (const int*)d_in[1];    // [B,N] int32
  const float* W    = (const float*)d_in[2];  // [C,H] fp32
  const float* bias = (const float*)d_in[3];  // [C] fp32

  const size_t need = (size_t)B_ * CHUNKS * N_ * C_ * sizeof(float);  // 576 KB
  const int use_atomic = (ws_size < need) ? 1 : 0;
  if (use_atomic)
    hipMemsetAsync(d_ws, 0, (size_t)B_ * N_ * C_ * sizeof(float), stream);

  seg_proj_kernel<<<B_ * CHUNKS, 256, 0, stream>>>(lhs, st, W, (float*)d_ws, use_atomic);
  finalize_kernel<<<(B_ * N_ * C_ + 255) / 256, 256, 0, stream>>>(
      (float*)d_ws, st, bias, (float*)d_out, use_atomic);
}